// Round 1
// baseline (280.675 us; speedup 1.0000x reference)
//
#include <hip/hip_runtime.h>
#include <math.h>

#define NCLS   100000
#define NBATCH 512

// SCALE = 64, MARGIN = 0.5, EPS = 1e-7
constexpr float SCALE = 64.0f;
constexpr float COS_M = 0.87758256189037276f;   // cos(0.5)
constexpr float SIN_M = 0.47942553860420301f;   // sin(0.5)
constexpr float EPSC  = 1e-7f;
// Fixed softmax reference m = SCALE*1.0 = 64 (upper bound of scaled logits).
// exp(SCALE*l - 64) = exp2(l*K - K), K = 64*log2(e).
constexpr float K = 92.33248261689366f;

// One block per row: stream 100000 floats, sum exp2(fma(l,K,-K)).
__global__ __launch_bounds__(1024) void arc_row_kernel(
    const float* __restrict__ logits,
    const int*   __restrict__ labels,
    float*       __restrict__ row_nll)
{
    const int row = blockIdx.x;
    const float* rowp = logits + (size_t)row * NCLS;
    const float4* rp4 = reinterpret_cast<const float4*>(rowp);

    float s0 = 0.f, s1 = 0.f, s2 = 0.f, s3 = 0.f;
    for (int i = threadIdx.x; i < NCLS / 4; i += 1024) {
        float4 v = rp4[i];
        s0 += exp2f(fmaf(v.x, K, -K));
        s1 += exp2f(fmaf(v.y, K, -K));
        s2 += exp2f(fmaf(v.z, K, -K));
        s3 += exp2f(fmaf(v.w, K, -K));
    }
    float lsum = (s0 + s1) + (s2 + s3);

    // wave64 butterfly-free down-reduce
    #pragma unroll
    for (int off = 32; off; off >>= 1)
        lsum += __shfl_down(lsum, off, 64);

    __shared__ float wsum[16];
    const int lane = threadIdx.x & 63;
    const int wid  = threadIdx.x >> 6;
    if (lane == 0) wsum[wid] = lsum;
    __syncthreads();

    if (threadIdx.x == 0) {
        float s = 0.f;
        #pragma unroll
        for (int i = 0; i < 16; ++i) s += wsum[i];

        const int   lbl = labels[row];
        const float xo  = rowp[lbl];                       // original target logit
        float x  = fminf(fmaxf(xo, -1.0f + EPSC), 1.0f - EPSC);
        // cos(arccos(x) + M) = x*cos(M) - sqrt(1-x^2)*sin(M)
        float xn = x * COS_M - sqrtf(fmaxf(1.0f - x * x, 0.0f)) * SIN_M;

        // swap target's contribution: remove old, add margin-transformed
        s += exp2f(fmaf(xn, K, -K)) - exp2f(fmaf(xo, K, -K));

        // logp_target = SCALE*xn - (64 + log(sum_fixed)); nll = -logp
        row_nll[row] = -(SCALE * xn - SCALE - logf(s));
    }
}

// Mean of 512 per-row NLLs -> scalar.
__global__ __launch_bounds__(512) void mean_kernel(
    const float* __restrict__ row_nll, float* __restrict__ out)
{
    float v = row_nll[threadIdx.x];
    #pragma unroll
    for (int off = 32; off; off >>= 1)
        v += __shfl_down(v, off, 64);

    __shared__ float wsum[8];
    const int lane = threadIdx.x & 63;
    const int wid  = threadIdx.x >> 6;
    if (lane == 0) wsum[wid] = v;
    __syncthreads();

    if (threadIdx.x == 0) {
        float t = 0.f;
        #pragma unroll
        for (int i = 0; i < 8; ++i) t += wsum[i];
        out[0] = t * (1.0f / NBATCH);
    }
}

extern "C" void kernel_launch(void* const* d_in, const int* in_sizes, int n_in,
                              void* d_out, int out_size, void* d_ws, size_t ws_size,
                              hipStream_t stream)
{
    const float* logits  = (const float*)d_in[0];
    const int*   labels  = (const int*)d_in[1];
    float*       out     = (float*)d_out;
    float*       row_nll = (float*)d_ws;   // 512 floats of scratch

    arc_row_kernel<<<NBATCH, 1024, 0, stream>>>(logits, labels, row_nll);
    mean_kernel<<<1, 512, 0, stream>>>(row_nll, out);
}

// Round 2
// 278.576 us; speedup vs baseline: 1.0075x; 1.0075x over previous
//
#include <hip/hip_runtime.h>
#include <math.h>

#define NCLS   100000
#define NBATCH 512

// SCALE = 64, MARGIN = 0.5, EPS = 1e-7
constexpr float SCALE = 64.0f;
constexpr float COS_M = 0.87758256189037276f;   // cos(0.5)
constexpr float SIN_M = 0.47942553860420301f;   // sin(0.5)
constexpr float EPSC  = 1e-7f;
// Fixed softmax reference m = SCALE*1.0 = 64 (upper bound of scaled logits).
// exp(SCALE*l - 64) = exp2(l*K - K), K = 64*log2(e). Args are <= 0; terms
// below 2^-126 flush to zero in v_exp_f32, which is numerically irrelevant
// (row max corresponds to arg ~ -0.002, dropped terms are < 1e-38 relative).
constexpr float K = 92.33248261689366f;

__device__ __forceinline__ float fexp2(float x) {
    return __builtin_amdgcn_exp2f(x);   // raw v_exp_f32, no OCML denormal guard
}

// One block per row: stream 100000 floats, sum exp2(fma(l,K,-K)).
// 25000 float4 = 24*1024 + 424  ->  uniform 24-trip loop + small tail.
// __launch_bounds__(1024, 8): VGPR <= 64 so 2 blocks/CU co-reside (32 waves/CU).
__global__ __launch_bounds__(1024, 8) void arc_row_kernel(
    const float* __restrict__ logits,
    const int*   __restrict__ labels,
    float*       __restrict__ row_nll)
{
    const int row = blockIdx.x;
    const int tid = threadIdx.x;
    const float* rowp = logits + (size_t)row * NCLS;
    const float4* rp4 = reinterpret_cast<const float4*>(rowp);

    // Prefetch the dependent label -> target-logit chain under the stream loop.
    int lbl = 0; float xo = 0.0f;
    if (tid == 0) { lbl = labels[row]; xo = rowp[lbl]; }

    float s0 = 0.f, s1 = 0.f, s2 = 0.f, s3 = 0.f;
    const float4* p = rp4 + tid;
    #pragma unroll 8
    for (int it = 0; it < 24; ++it) {          // uniform trip count: 8 loads in flight
        float4 v = p[it * 1024];
        s0 += fexp2(fmaf(v.x, K, -K));
        s1 += fexp2(fmaf(v.y, K, -K));
        s2 += fexp2(fmaf(v.z, K, -K));
        s3 += fexp2(fmaf(v.w, K, -K));
    }
    if (tid < 424) {                           // tail: 24*1024 .. 24999
        float4 v = p[24 * 1024];
        s0 += fexp2(fmaf(v.x, K, -K));
        s1 += fexp2(fmaf(v.y, K, -K));
        s2 += fexp2(fmaf(v.z, K, -K));
        s3 += fexp2(fmaf(v.w, K, -K));
    }
    float lsum = (s0 + s1) + (s2 + s3);

    #pragma unroll
    for (int off = 32; off; off >>= 1)
        lsum += __shfl_down(lsum, off, 64);

    __shared__ float wsum[16];
    if ((tid & 63) == 0) wsum[tid >> 6] = lsum;
    __syncthreads();

    if (tid == 0) {
        float s = 0.f;
        #pragma unroll
        for (int i = 0; i < 16; ++i) s += wsum[i];

        float x  = fminf(fmaxf(xo, -1.0f + EPSC), 1.0f - EPSC);
        // cos(arccos(x) + M) = x*cos(M) - sqrt(1-x^2)*sin(M)
        float xn = x * COS_M - sqrtf(fmaxf(1.0f - x * x, 0.0f)) * SIN_M;

        // swap target's contribution: remove old, add margin-transformed
        s += fexp2(fmaf(xn, K, -K)) - fexp2(fmaf(xo, K, -K));

        // logp_target = SCALE*xn - (64 + log(sum_fixed)); nll = -logp
        row_nll[row] = -(SCALE * xn - SCALE - logf(s));
    }
}

// Mean of 512 per-row NLLs -> scalar.
__global__ __launch_bounds__(512) void mean_kernel(
    const float* __restrict__ row_nll, float* __restrict__ out)
{
    float v = row_nll[threadIdx.x];
    #pragma unroll
    for (int off = 32; off; off >>= 1)
        v += __shfl_down(v, off, 64);

    __shared__ float wsum[8];
    if ((threadIdx.x & 63) == 0) wsum[threadIdx.x >> 6] = v;
    __syncthreads();

    if (threadIdx.x == 0) {
        float t = 0.f;
        #pragma unroll
        for (int i = 0; i < 8; ++i) t += wsum[i];
        out[0] = t * (1.0f / NBATCH);
    }
}

extern "C" void kernel_launch(void* const* d_in, const int* in_sizes, int n_in,
                              void* d_out, int out_size, void* d_ws, size_t ws_size,
                              hipStream_t stream)
{
    const float* logits  = (const float*)d_in[0];
    const int*   labels  = (const int*)d_in[1];
    float*       out     = (float*)d_out;
    float*       row_nll = (float*)d_ws;   // 512 floats of scratch

    arc_row_kernel<<<NBATCH, 1024, 0, stream>>>(logits, labels, row_nll);
    mean_kernel<<<1, 512, 0, stream>>>(row_nll, out);
}